// Round 2
// baseline (2099.963 us; speedup 1.0000x reference)
//
#include <hip/hip_runtime.h>
#include <stdint.h>

#define Q    2048
#define NB   40000
#define NK   2048
#define ND   512
#define SCORE_SIZE (Q * NB)   // 81,920,000

typedef __bf16 bf16;
typedef bf16  bf16x8 __attribute__((ext_vector_type(8)));
typedef float f32x4  __attribute__((ext_vector_type(4)));

__device__ __forceinline__ unsigned short f2bf_rne(float f) {
    unsigned int u = __float_as_uint(f);
    u += 0x7FFFu + ((u >> 16) & 1u);
    return (unsigned short)(u >> 16);
}
__device__ __forceinline__ float bf2f(unsigned short h) {
    return __uint_as_float((unsigned int)h << 16);
}
// truncation split of a pair of floats into packed bf16 hi / bf16 lo
__device__ __forceinline__ void split_pair_trunc(float x0, float x1,
                                                 unsigned int& hp, unsigned int& lp) {
    unsigned int u0 = __float_as_uint(x0), u1 = __float_as_uint(x1);
    hp = (u0 >> 16) | (u1 & 0xFFFF0000u);
    float l0 = x0 - __uint_as_float(u0 & 0xFFFF0000u);
    float l1 = x1 - __uint_as_float(u1 & 0xFFFF0000u);
    lp = (__float_as_uint(l0) >> 16) | (__float_as_uint(l1) & 0xFFFF0000u);
}

// ---------------------------------------------------------------- c2 = ||cb_k||^2
__global__ __launch_bounds__(256) void c2_kernel(const float* __restrict__ cb,
                                                 float* __restrict__ c2) {
    int wave = threadIdx.x >> 6, lane = threadIdx.x & 63;
    int row  = blockIdx.x * 4 + wave;          // grid = NK/4 = 512
    const float4* p = (const float4*)(cb + (size_t)row * ND);
    float4 a = p[lane];
    float4 b = p[lane + 64];
    float s = a.x*a.x + a.y*a.y + a.z*a.z + a.w*a.w
            + b.x*b.x + b.y*b.y + b.z*b.z + b.w*b.w;
    #pragma unroll
    for (int off = 32; off; off >>= 1) s += __shfl_down(s, off);
    if (lane == 0) c2[row] = s;
}

// ---------------------------------------------------- codebook hi/lo split (RNE)
__global__ __launch_bounds__(256) void cvt_cb_kernel(const float* __restrict__ cb,
        unsigned short* __restrict__ chi, unsigned short* __restrict__ clo) {
    int i = (blockIdx.x * 256 + threadIdx.x) * 4;     // grid = NK*ND/1024 = 1024
    float4 v = *(const float4*)(cb + i);
    unsigned short h[4]; float l[4];
    float x[4] = {v.x, v.y, v.z, v.w};
    #pragma unroll
    for (int j = 0; j < 4; ++j) { h[j] = f2bf_rne(x[j]); l[j] = x[j] - bf2f(h[j]); }
    uint2 hp, lp;
    hp.x = (unsigned int)h[0] | ((unsigned int)h[1] << 16);
    hp.y = (unsigned int)h[2] | ((unsigned int)h[3] << 16);
    lp.x = (unsigned int)f2bf_rne(l[0]) | ((unsigned int)f2bf_rne(l[1]) << 16);
    lp.y = (unsigned int)f2bf_rne(l[2]) | ((unsigned int)f2bf_rne(l[3]) << 16);
    *(uint2*)(chi + i) = hp;
    *(uint2*)(clo + i) = lp;
}

// ---------------------------------------------------- entity hi/lo split (RNE)
__global__ __launch_bounds__(256) void cvt_ent_kernel(const float* __restrict__ ent,
        unsigned short* __restrict__ ehi, unsigned short* __restrict__ elo) {
    int i = (blockIdx.x * 256 + threadIdx.x) * 4;     // grid = NB*ND/1024 = 20000
    float4 v = *(const float4*)(ent + i);
    unsigned short h[4]; float l[4];
    float x[4] = {v.x, v.y, v.z, v.w};
    #pragma unroll
    for (int j = 0; j < 4; ++j) { h[j] = f2bf_rne(x[j]); l[j] = x[j] - bf2f(h[j]); }
    uint2 hp, lp;
    hp.x = (unsigned int)h[0] | ((unsigned int)h[1] << 16);
    hp.y = (unsigned int)h[2] | ((unsigned int)h[3] << 16);
    lp.x = (unsigned int)f2bf_rne(l[0]) | ((unsigned int)f2bf_rne(l[1]) << 16);
    lp.y = (unsigned int)f2bf_rne(l[2]) | ((unsigned int)f2bf_rne(l[3]) << 16);
    *(uint2*)(ehi + i) = hp;
    *(uint2*)(elo + i) = lp;
}

// top-2 insert with first-index tie-break
__device__ __forceinline__ void top2_insert(float& v1, int& i1, float& v2, int& i2,
                                            float w, int j) {
    if (w < v1 || (w == v1 && j < i1)) { v2 = v1; i2 = i1; v1 = w; i1 = j; }
    else if (w < v2 || (w == v2 && j < i2)) { v2 = w; i2 = j; }
}

// --------------------- approx distance GEMM via hi/lo bf16 MFMA + per-group top-2
// s(b,k) = c2[k] - 2*(hx.hc + hx.lc + lx.hc)   (lx.lc dropped, |err| <~ 1e-3)
// tile 128 entities x 128 codes, BK=32, grid (313, 16); 4 waves 2x2, 64x64 each.
// partial[(kt*2+wn)*NB + b] = float4(v1, idx1, v2, idx2) over that 64-code group.
template<bool PRE>
__global__ __launch_bounds__(256) void dist_mfma_kernel(
        const float* __restrict__ entf,
        const unsigned short* __restrict__ ehi, const unsigned short* __restrict__ elo,
        const unsigned short* __restrict__ chi, const unsigned short* __restrict__ clo,
        const float* __restrict__ c2g, float4* __restrict__ partial) {
    __shared__ unsigned short EH[128 * 32];
    __shared__ unsigned short EL[128 * 32];
    __shared__ unsigned short CH[128 * 32];
    __shared__ unsigned short CL[128 * 32];
    int tid = threadIdx.x;
    int b0 = blockIdx.x * 128;
    int k0 = blockIdx.y * 128;
    int lane = tid & 63, wave = tid >> 6;
    int wm = wave >> 1, wn = wave & 1;
    int lr = lane & 15, quad = lane >> 4;

    f32x4 acc[4][4] = {};

    for (int kt = 0; kt < ND; kt += 32) {
        __syncthreads();
        #pragma unroll
        for (int r = 0; r < 2; ++r) {
            int e = r * 256 + tid;             // 512 chunks of 8 bf16 per matrix
            int row = e >> 2, cc = e & 3;
            int br = b0 + row; br = br < NB ? br : NB - 1;
            size_t eoff = (size_t)br * ND + kt + cc * 8;
            if (PRE) {
                *(uint4*)(EH + row * 32 + cc * 8) = *(const uint4*)(ehi + eoff);
                *(uint4*)(EL + row * 32 + cc * 8) = *(const uint4*)(elo + eoff);
            } else {
                const float* src = entf + eoff;
                float4 a = *(const float4*)src;
                float4 b = *(const float4*)(src + 4);
                uint4 hp, lp;
                split_pair_trunc(a.x, a.y, hp.x, lp.x);
                split_pair_trunc(a.z, a.w, hp.y, lp.y);
                split_pair_trunc(b.x, b.y, hp.z, lp.z);
                split_pair_trunc(b.z, b.w, hp.w, lp.w);
                *(uint4*)(EH + row * 32 + cc * 8) = hp;
                *(uint4*)(EL + row * 32 + cc * 8) = lp;
            }
            size_t coff = (size_t)(k0 + row) * ND + kt + cc * 8;
            *(uint4*)(CH + row * 32 + cc * 8) = *(const uint4*)(chi + coff);
            *(uint4*)(CL + row * 32 + cc * 8) = *(const uint4*)(clo + coff);
        }
        __syncthreads();
        bf16x8 ah[4], al[4], bh[4], bl[4];
        #pragma unroll
        for (int mi = 0; mi < 4; ++mi) {
            int o = (wm * 64 + mi * 16 + lr) * 32 + quad * 8;
            ah[mi] = *(const bf16x8*)(EH + o);
            al[mi] = *(const bf16x8*)(EL + o);
        }
        #pragma unroll
        for (int ni = 0; ni < 4; ++ni) {
            int o = (wn * 64 + ni * 16 + lr) * 32 + quad * 8;
            bh[ni] = *(const bf16x8*)(CH + o);
            bl[ni] = *(const bf16x8*)(CL + o);
        }
        #pragma unroll
        for (int mi = 0; mi < 4; ++mi)
            #pragma unroll
            for (int ni = 0; ni < 4; ++ni) {
                acc[mi][ni] = __builtin_amdgcn_mfma_f32_16x16x32_bf16(
                    ah[mi], bh[ni], acc[mi][ni], 0, 0, 0);
                acc[mi][ni] = __builtin_amdgcn_mfma_f32_16x16x32_bf16(
                    ah[mi], bl[ni], acc[mi][ni], 0, 0, 0);
                acc[mi][ni] = __builtin_amdgcn_mfma_f32_16x16x32_bf16(
                    al[mi], bh[ni], acc[mi][ni], 0, 0, 0);
            }
    }

    // per-row top-2 over this wave's 64-code group, then write to partial
    float c2v[4];
    #pragma unroll
    for (int ni = 0; ni < 4; ++ni) c2v[ni] = c2g[k0 + wn * 64 + ni * 16 + lr];

    #pragma unroll
    for (int mi = 0; mi < 4; ++mi) {
        #pragma unroll
        for (int rr = 0; rr < 4; ++rr) {
            float v1 = 3.4e38f, v2 = 3.4e38f;
            int i1 = 0x7FFFFFFF, i2 = 0x7FFFFFFF;
            #pragma unroll
            for (int ni = 0; ni < 4; ++ni) {
                float w = c2v[ni] - 2.0f * acc[mi][ni][rr];
                top2_insert(v1, i1, v2, i2, w, k0 + wn * 64 + ni * 16 + lr);
            }
            #pragma unroll
            for (int off = 1; off < 16; off <<= 1) {
                float ov1 = __shfl_xor(v1, off); int oi1 = __shfl_xor(i1, off);
                float ov2 = __shfl_xor(v2, off); int oi2 = __shfl_xor(i2, off);
                top2_insert(v1, i1, v2, i2, ov1, oi1);
                top2_insert(v1, i1, v2, i2, ov2, oi2);
            }
            int b = b0 + wm * 64 + mi * 16 + quad * 4 + rr;
            if (lr == 0 && b < NB)
                partial[(size_t)(blockIdx.y * 2 + wn) * NB + b] =
                    make_float4(v1, __int_as_float(i1), v2, __int_as_float(i2));
        }
    }
}

// ------------------------------ merge 32 group top-2s -> global approx top-4
__global__ __launch_bounds__(256) void cand_merge_kernel(
        const float4* __restrict__ partial, int* __restrict__ cand) {
    int b = blockIdx.x * 256 + threadIdx.x;
    if (b >= NB) return;
    float tv[4] = {3.4e38f, 3.4e38f, 3.4e38f, 3.4e38f};
    int   ti[4] = {0x7FFFFFFF, 0x7FFFFFFF, 0x7FFFFFFF, 0x7FFFFFFF};
    for (int g = 0; g < 32; ++g) {
        float4 p = partial[(size_t)g * NB + b];
        float pv[2] = {p.x, p.z};
        int   pi[2] = {__float_as_int(p.y), __float_as_int(p.w)};
        #pragma unroll
        for (int t = 0; t < 2; ++t) {
            float w = pv[t]; int j = pi[t];
            #pragma unroll
            for (int s = 0; s < 4; ++s) {
                if (w < tv[s] || (w == tv[s] && j < ti[s])) {
                    float tmpv = tv[s]; int tmpi = ti[s];
                    tv[s] = w; ti[s] = j; w = tmpv; j = tmpi;
                }
            }
        }
    }
    #pragma unroll
    for (int s = 0; s < 4; ++s) cand[b * 4 + s] = ti[s];
}

// ------- exact fp32 rescore of 4 candidates + fused quant gather + vq_loss
__global__ __launch_bounds__(256) void rescore_kernel(
        const float* __restrict__ ent, const float* __restrict__ cb,
        const float* __restrict__ c2g, const int* __restrict__ cand,
        unsigned short* __restrict__ quantb, float* __restrict__ out_idx,
        float* __restrict__ acc) {
    int b = blockIdx.x;                 // grid = NB
    int wave = threadIdx.x >> 6, lane = threadIdx.x & 63;
    int k = cand[b * 4 + wave];
    const float4* xp = (const float4*)(ent + (size_t)b * ND);
    const float4* cp = (const float4*)(cb + (size_t)k * ND);
    float4 x0 = xp[lane * 2], x1 = xp[lane * 2 + 1];
    float4 c0 = cp[lane * 2], c1 = cp[lane * 2 + 1];
    float s = x0.x*c0.x + x0.y*c0.y + x0.z*c0.z + x0.w*c0.w
            + x1.x*c1.x + x1.y*c1.y + x1.z*c1.z + x1.w*c1.w;
    #pragma unroll
    for (int off = 32; off; off >>= 1) s += __shfl_down(s, off);
    __shared__ float vws[4];
    __shared__ int   kws[4];
    __shared__ int   win;
    if (lane == 0) { vws[wave] = c2g[k] - 2.0f * s; kws[wave] = k; }
    __syncthreads();
    if (threadIdx.x == 0) {
        float bv = vws[0]; int bk = kws[0], bw = 0;
        #pragma unroll
        for (int w = 1; w < 4; ++w) {
            if (vws[w] < bv || (vws[w] == bv && kws[w] < bk)) {
                bv = vws[w]; bk = kws[w]; bw = w;
            }
        }
        win = bw;
        out_idx[b] = (float)bk;
    }
    __syncthreads();
    if (wave == win) {
        // quant (bf16) write for the score GEMM
        uint4 qp;
        qp.x = (unsigned int)f2bf_rne(c0.x) | ((unsigned int)f2bf_rne(c0.y) << 16);
        qp.y = (unsigned int)f2bf_rne(c0.z) | ((unsigned int)f2bf_rne(c0.w) << 16);
        qp.z = (unsigned int)f2bf_rne(c1.x) | ((unsigned int)f2bf_rne(c1.y) << 16);
        qp.w = (unsigned int)f2bf_rne(c1.z) | ((unsigned int)f2bf_rne(c1.w) << 16);
        *(uint4*)(quantb + (size_t)b * ND + lane * 8) = qp;
        float d0 = c0.x - x0.x, d1 = c0.y - x0.y, d2 = c0.z - x0.z, d3 = c0.w - x0.w;
        float d4 = c1.x - x1.x, d5 = c1.y - x1.y, d6 = c1.z - x1.z, d7 = c1.w - x1.w;
        float l = d0*d0 + d1*d1 + d2*d2 + d3*d3 + d4*d4 + d5*d5 + d6*d6 + d7*d7;
        #pragma unroll
        for (int off = 32; off; off >>= 1) l += __shfl_down(l, off);
        if (lane == 0) atomicAdd(acc, l);
    }
}

__global__ void vq_final_kernel(const float* __restrict__ acc, float* __restrict__ out) {
    out[0] = 1.25f * acc[0] / (float)(NB * ND);
}

// ---------------------------------------------------------- query -> bf16
__global__ __launch_bounds__(256) void qcvt_kernel(const float* __restrict__ qry,
                                                   unsigned short* __restrict__ qb) {
    int i = (blockIdx.x * 256 + threadIdx.x) * 4;   // grid = Q*ND/1024 = 1024
    float4 v = *(const float4*)(qry + i);
    uint2 u;
    u.x = (unsigned int)f2bf_rne(v.x) | ((unsigned int)f2bf_rne(v.y) << 16);
    u.y = (unsigned int)f2bf_rne(v.z) | ((unsigned int)f2bf_rne(v.w) << 16);
    *(uint2*)(qb + i) = u;
}

// --------------------------- score = query @ quant^T, bf16 MFMA 128x128x32 tiles
__global__ __launch_bounds__(256) void score_kernel(
        const unsigned short* __restrict__ Aq, const unsigned short* __restrict__ Bq,
        float* __restrict__ C) {
    __shared__ unsigned short As[128 * 32];
    __shared__ unsigned short Bs[128 * 32];
    int tid = threadIdx.x;
    int n0 = blockIdx.x * 128;
    int m0 = blockIdx.y * 128;
    int lane = tid & 63, wave = tid >> 6;
    int wm = wave >> 1, wn = wave & 1;
    int lr = lane & 15, quad = lane >> 4;

    f32x4 acc[4][4] = {};

    for (int kt = 0; kt < ND; kt += 32) {
        __syncthreads();
        #pragma unroll
        for (int r = 0; r < 2; ++r) {
            int e = r * 256 + tid;
            int row = e >> 2, cc = e & 3;
            uint4 va = *(const uint4*)(Aq + (size_t)(m0 + row) * ND + kt + cc * 8);
            *(uint4*)(As + row * 32 + cc * 8) = va;
            int nr = n0 + row; nr = nr < NB ? nr : NB - 1;
            uint4 vb = *(const uint4*)(Bq + (size_t)nr * ND + kt + cc * 8);
            *(uint4*)(Bs + row * 32 + cc * 8) = vb;
        }
        __syncthreads();
        bf16x8 af[4], bfr[4];
        #pragma unroll
        for (int mi = 0; mi < 4; ++mi)
            af[mi] = *(const bf16x8*)(As + (wm * 64 + mi * 16 + lr) * 32 + quad * 8);
        #pragma unroll
        for (int ni = 0; ni < 4; ++ni)
            bfr[ni] = *(const bf16x8*)(Bs + (wn * 64 + ni * 16 + lr) * 32 + quad * 8);
        #pragma unroll
        for (int mi = 0; mi < 4; ++mi)
            #pragma unroll
            for (int ni = 0; ni < 4; ++ni)
                acc[mi][ni] = __builtin_amdgcn_mfma_f32_16x16x32_bf16(
                    af[mi], bfr[ni], acc[mi][ni], 0, 0, 0);
    }

    #pragma unroll
    for (int mi = 0; mi < 4; ++mi) {
        #pragma unroll
        for (int ni = 0; ni < 4; ++ni) {
            int col = n0 + wn * 64 + ni * 16 + lr;
            if (col < NB) {
                #pragma unroll
                for (int r = 0; r < 4; ++r) {
                    int row = m0 + wm * 64 + mi * 16 + quad * 4 + r;
                    C[(size_t)row * NB + col] = acc[mi][ni][r];
                }
            }
        }
    }
}

extern "C" void kernel_launch(void* const* d_in, const int* in_sizes, int n_in,
                              void* d_out, int out_size, void* d_ws, size_t ws_size,
                              hipStream_t stream) {
    const float* qry = (const float*)d_in[0];   // (2048, 512)
    const float* ent = (const float*)d_in[1];   // (40000, 512)
    const float* cb  = (const float*)d_in[2];   // (2048, 512)
    float* out = (float*)d_out;                 // [score | vq_loss | idx]

    char* ws = (char*)d_ws;
    const bool pre = ws_size >= 130ull * 1024 * 1024;

    // region0: partial (20.48 MB) during dist, then quantb (40.96 MB) — ordering-safe alias
    float4*         partial = (float4*)(ws);
    unsigned short* quantb  = (unsigned short*)(ws);
    size_t off = 40960000;
    unsigned short *ehi = nullptr, *elo = nullptr;
    if (pre) {
        ehi = (unsigned short*)(ws + off); off += 40960000;
        elo = (unsigned short*)(ws + off); off += 40960000;
    }
    unsigned short* chi = (unsigned short*)(ws + off); off += 2097152;
    unsigned short* clo = (unsigned short*)(ws + off); off += 2097152;
    unsigned short* qb  = (unsigned short*)(ws + off); off += 2097152;
    int*            cand= (int*)(ws + off);            off += 640000;
    float*          c2  = (float*)(ws + off);          off += 8192;
    float*          acc = (float*)(ws + off);          off += 4;

    hipMemsetAsync(acc, 0, sizeof(float), stream);

    c2_kernel<<<NK / 4, 256, 0, stream>>>(cb, c2);
    cvt_cb_kernel<<<1024, 256, 0, stream>>>(cb, chi, clo);
    qcvt_kernel<<<1024, 256, 0, stream>>>(qry, qb);
    if (pre) {
        cvt_ent_kernel<<<20000, 256, 0, stream>>>(ent, ehi, elo);
        dist_mfma_kernel<true><<<dim3(313, 16), 256, 0, stream>>>(
            ent, ehi, elo, chi, clo, c2, partial);
    } else {
        dist_mfma_kernel<false><<<dim3(313, 16), 256, 0, stream>>>(
            ent, nullptr, nullptr, chi, clo, c2, partial);
    }
    cand_merge_kernel<<<(NB + 255) / 256, 256, 0, stream>>>(partial, cand);
    rescore_kernel<<<NB, 256, 0, stream>>>(ent, cb, c2, cand, quantb,
                                           out + SCORE_SIZE + 1, acc);
    vq_final_kernel<<<1, 1, 0, stream>>>(acc, out + SCORE_SIZE);
    score_kernel<<<dim3(313, 16), 256, 0, stream>>>(qb, quantb, out);
}

// Round 3
// 1957.045 us; speedup vs baseline: 1.0730x; 1.0730x over previous
//
#include <hip/hip_runtime.h>
#include <stdint.h>

#define Q    2048
#define NB   40000
#define NK   2048
#define ND   512
#define SCORE_SIZE (Q * NB)   // 81,920,000

typedef __bf16 bf16;
typedef bf16  bf16x8 __attribute__((ext_vector_type(8)));
typedef float f32x4  __attribute__((ext_vector_type(4)));

__device__ __forceinline__ unsigned short f2bf_rne(float f) {
    unsigned int u = __float_as_uint(f);
    u += 0x7FFFu + ((u >> 16) & 1u);
    return (unsigned short)(u >> 16);
}

// async global->LDS 16B: LDS side is wave-uniform base + lane*16 (m97/m104)
__device__ __forceinline__ void gl2lds16(const void* g, void* l) {
    __builtin_amdgcn_global_load_lds(
        (const __attribute__((address_space(1))) void*)g,
        (__attribute__((address_space(3))) void*)l, 16, 0, 0);
}

// ---------------------------------------------------------------- c2 = ||cb_k||^2
__global__ __launch_bounds__(256) void c2_kernel(const float* __restrict__ cb,
                                                 float* __restrict__ c2) {
    int wave = threadIdx.x >> 6, lane = threadIdx.x & 63;
    int row  = blockIdx.x * 4 + wave;          // grid = NK/4 = 512
    const float4* p = (const float4*)(cb + (size_t)row * ND);
    float4 a = p[lane];
    float4 b = p[lane + 64];
    float s = a.x*a.x + a.y*a.y + a.z*a.z + a.w*a.w
            + b.x*b.x + b.y*b.y + b.z*b.z + b.w*b.w;
    #pragma unroll
    for (int off = 32; off; off >>= 1) s += __shfl_down(s, off);
    if (lane == 0) c2[row] = s;
}

// ---------------------------------------------------------- fp32 -> bf16 (RNE)
__global__ __launch_bounds__(256) void cvt_bf16_kernel(const float* __restrict__ src,
                                                       unsigned short* __restrict__ dst) {
    int i = (blockIdx.x * 256 + threadIdx.x) * 4;
    float4 v = *(const float4*)(src + i);
    uint2 u;
    u.x = (unsigned int)f2bf_rne(v.x) | ((unsigned int)f2bf_rne(v.y) << 16);
    u.y = (unsigned int)f2bf_rne(v.z) | ((unsigned int)f2bf_rne(v.w) << 16);
    *(uint2*)(dst + i) = u;
}

// top-2 insert with first-index tie-break
__device__ __forceinline__ void top2_insert(float& v1, int& i1, float& v2, int& i2,
                                            float w, int j) {
    if (w < v1 || (w == v1 && j < i1)) { v2 = v1; i2 = i1; v1 = w; i1 = j; }
    else if (w < v2 || (w == v2 && j < i2)) { v2 = w; i2 = j; }
}

// ---------------- approx distance GEMM: s(b,k) = c2[k] - 2*bf16dot(x_b, c_k)
// m97-style: tile 128x128, BK=64, async global_load_lds, XOR chunk swizzle.
// LDS layout: row r (128B = 8 chunks of 16B), global chunk c stored at c^(r&7).
// grid (313, 16); 4 waves 2x2, 64x64 each; epilogue: top-2 per 64-code group.
template<bool PRE>
__global__ __launch_bounds__(256) void dist_mfma_kernel(
        const float* __restrict__ entf, const unsigned short* __restrict__ ehi,
        const unsigned short* __restrict__ chi,
        const float* __restrict__ c2g, float4* __restrict__ partial) {
    __shared__ unsigned short Es[128 * 64];   // 16 KB
    __shared__ unsigned short Cs[128 * 64];   // 16 KB
    int tid = threadIdx.x;
    int b0 = blockIdx.x * 128;
    int k0 = blockIdx.y * 128;
    int lane = tid & 63, wave = tid >> 6;
    int wm = wave >> 1, wn = wave & 1;
    int lr = lane & 15, quad = lane >> 4;

    f32x4 acc[4][4] = {};

    for (int kt = 0; kt < ND; kt += 64) {
        __syncthreads();
        #pragma unroll
        for (int j = 0; j < 4; ++j) {
            int q = j * 256 + tid;            // linear LDS chunk id, = lane-linear
            int r = q >> 3;
            int cs = (q & 7) ^ (r & 7);       // which global chunk lands here
            // codebook side: always async
            gl2lds16(chi + (size_t)(k0 + r) * ND + kt + cs * 8,
                     Cs + (size_t)(j * 256 + wave * 64) * 8);   // wave-uniform base
            int br = b0 + r; br = br < NB ? br : NB - 1;
            if (PRE) {
                gl2lds16(ehi + (size_t)br * ND + kt + cs * 8,
                         Es + (size_t)(j * 256 + wave * 64) * 8);
            } else {
                const float* s = entf + (size_t)br * ND + kt + cs * 8;
                float4 a = *(const float4*)s;
                float4 b = *(const float4*)(s + 4);
                uint4 hp;
                hp.x = (unsigned int)f2bf_rne(a.x) | ((unsigned int)f2bf_rne(a.y) << 16);
                hp.y = (unsigned int)f2bf_rne(a.z) | ((unsigned int)f2bf_rne(a.w) << 16);
                hp.z = (unsigned int)f2bf_rne(b.x) | ((unsigned int)f2bf_rne(b.y) << 16);
                hp.w = (unsigned int)f2bf_rne(b.z) | ((unsigned int)f2bf_rne(b.w) << 16);
                *(uint4*)(Es + q * 8) = hp;
            }
        }
        __syncthreads();
        #pragma unroll
        for (int kq = 0; kq < 2; ++kq) {
            bf16x8 af[4], bfr[4];
            #pragma unroll
            for (int mi = 0; mi < 4; ++mi) {
                int r = wm * 64 + mi * 16 + lr;
                int ch = (kq * 4 + quad) ^ (lr & 7);
                af[mi] = *(const bf16x8*)(Es + (r * 8 + ch) * 8);
            }
            #pragma unroll
            for (int ni = 0; ni < 4; ++ni) {
                int r = wn * 64 + ni * 16 + lr;
                int ch = (kq * 4 + quad) ^ (lr & 7);
                bfr[ni] = *(const bf16x8*)(Cs + (r * 8 + ch) * 8);
            }
            #pragma unroll
            for (int mi = 0; mi < 4; ++mi)
                #pragma unroll
                for (int ni = 0; ni < 4; ++ni)
                    acc[mi][ni] = __builtin_amdgcn_mfma_f32_16x16x32_bf16(
                        af[mi], bfr[ni], acc[mi][ni], 0, 0, 0);
        }
    }

    float c2v[4];
    #pragma unroll
    for (int ni = 0; ni < 4; ++ni) c2v[ni] = c2g[k0 + wn * 64 + ni * 16 + lr];

    #pragma unroll
    for (int mi = 0; mi < 4; ++mi) {
        #pragma unroll
        for (int rr = 0; rr < 4; ++rr) {
            float v1 = 3.4e38f, v2 = 3.4e38f;
            int i1 = 0x7FFFFFFF, i2 = 0x7FFFFFFF;
            #pragma unroll
            for (int ni = 0; ni < 4; ++ni) {
                float w = c2v[ni] - 2.0f * acc[mi][ni][rr];
                top2_insert(v1, i1, v2, i2, w, k0 + wn * 64 + ni * 16 + lr);
            }
            #pragma unroll
            for (int off = 1; off < 16; off <<= 1) {
                float ov1 = __shfl_xor(v1, off); int oi1 = __shfl_xor(i1, off);
                float ov2 = __shfl_xor(v2, off); int oi2 = __shfl_xor(i2, off);
                top2_insert(v1, i1, v2, i2, ov1, oi1);
                top2_insert(v1, i1, v2, i2, ov2, oi2);
            }
            int b = b0 + wm * 64 + mi * 16 + quad * 4 + rr;
            if (lr == 0 && b < NB)
                partial[(size_t)(blockIdx.y * 2 + wn) * NB + b] =
                    make_float4(v1, __int_as_float(i1), v2, __int_as_float(i2));
        }
    }
}

// ------------------------------ merge 32 group top-2s -> global approx top-8
__global__ __launch_bounds__(256) void cand_merge_kernel(
        const float4* __restrict__ partial, int* __restrict__ cand) {
    int b = blockIdx.x * 256 + threadIdx.x;
    if (b >= NB) return;
    float tv[8]; int ti[8];
    #pragma unroll
    for (int s = 0; s < 8; ++s) { tv[s] = 3.4e38f; ti[s] = 0x7FFFFFFF; }
    for (int g = 0; g < 32; ++g) {
        float4 p = partial[(size_t)g * NB + b];
        float pv[2] = {p.x, p.z};
        int   pi[2] = {__float_as_int(p.y), __float_as_int(p.w)};
        #pragma unroll
        for (int t = 0; t < 2; ++t) {
            float w = pv[t]; int j = pi[t];
            #pragma unroll
            for (int s = 0; s < 8; ++s) {
                if (w < tv[s] || (w == tv[s] && j < ti[s])) {
                    float tmpv = tv[s]; int tmpi = ti[s];
                    tv[s] = w; ti[s] = j; w = tmpv; j = tmpi;
                }
            }
        }
    }
    #pragma unroll
    for (int s = 0; s < 8; ++s) cand[(size_t)b * 8 + s] = ti[s];
}

// ------- exact fp32 rescore of 8 candidates + fused quant gather + vq_loss
__global__ __launch_bounds__(512) void rescore_kernel(
        const float* __restrict__ ent, const float* __restrict__ cb,
        const float* __restrict__ c2g, const int* __restrict__ cand,
        unsigned short* __restrict__ quantb, float* __restrict__ out_idx,
        float* __restrict__ acc) {
    int b = blockIdx.x;                 // grid = NB, 8 waves = 8 candidates
    int wave = threadIdx.x >> 6, lane = threadIdx.x & 63;
    int k = cand[(size_t)b * 8 + wave];
    const float4* xp = (const float4*)(ent + (size_t)b * ND);
    const float4* cp = (const float4*)(cb + (size_t)k * ND);
    float4 x0 = xp[lane * 2], x1 = xp[lane * 2 + 1];
    float4 c0 = cp[lane * 2], c1 = cp[lane * 2 + 1];
    float s = x0.x*c0.x + x0.y*c0.y + x0.z*c0.z + x0.w*c0.w
            + x1.x*c1.x + x1.y*c1.y + x1.z*c1.z + x1.w*c1.w;
    #pragma unroll
    for (int off = 32; off; off >>= 1) s += __shfl_down(s, off);
    __shared__ float vws[8];
    __shared__ int   kws[8];
    __shared__ int   win;
    if (lane == 0) { vws[wave] = c2g[k] - 2.0f * s; kws[wave] = k; }
    __syncthreads();
    if (threadIdx.x == 0) {
        float bv = vws[0]; int bk = kws[0], bw = 0;
        #pragma unroll
        for (int w = 1; w < 8; ++w) {
            if (vws[w] < bv || (vws[w] == bv && kws[w] < bk)) {
                bv = vws[w]; bk = kws[w]; bw = w;
            }
        }
        win = bw;
        out_idx[b] = (float)bk;
    }
    __syncthreads();
    if (wave == win) {
        uint4 qp;
        qp.x = (unsigned int)f2bf_rne(c0.x) | ((unsigned int)f2bf_rne(c0.y) << 16);
        qp.y = (unsigned int)f2bf_rne(c0.z) | ((unsigned int)f2bf_rne(c0.w) << 16);
        qp.z = (unsigned int)f2bf_rne(c1.x) | ((unsigned int)f2bf_rne(c1.y) << 16);
        qp.w = (unsigned int)f2bf_rne(c1.z) | ((unsigned int)f2bf_rne(c1.w) << 16);
        *(uint4*)(quantb + (size_t)b * ND + lane * 8) = qp;
        float d0 = c0.x - x0.x, d1 = c0.y - x0.y, d2 = c0.z - x0.z, d3 = c0.w - x0.w;
        float d4 = c1.x - x1.x, d5 = c1.y - x1.y, d6 = c1.z - x1.z, d7 = c1.w - x1.w;
        float l = d0*d0 + d1*d1 + d2*d2 + d3*d3 + d4*d4 + d5*d5 + d6*d6 + d7*d7;
        #pragma unroll
        for (int off = 32; off; off >>= 1) l += __shfl_down(l, off);
        if (lane == 0) atomicAdd(acc, l);
    }
}

__global__ void vq_final_kernel(const float* __restrict__ acc, float* __restrict__ out) {
    out[0] = 1.25f * acc[0] / (float)(NB * ND);
}

// ---------- score = query @ quant^T, m97-style: BK=64, async staging, swizzle
__global__ __launch_bounds__(256) void score_kernel(
        const unsigned short* __restrict__ Aq, const unsigned short* __restrict__ Bq,
        float* __restrict__ C) {
    __shared__ unsigned short As[128 * 64];
    __shared__ unsigned short Bs[128 * 64];
    int tid = threadIdx.x;
    int n0 = blockIdx.x * 128;
    int m0 = blockIdx.y * 128;
    int lane = tid & 63, wave = tid >> 6;
    int wm = wave >> 1, wn = wave & 1;
    int lr = lane & 15, quad = lane >> 4;

    f32x4 acc[4][4] = {};

    for (int kt = 0; kt < ND; kt += 64) {
        __syncthreads();
        #pragma unroll
        for (int j = 0; j < 4; ++j) {
            int q = j * 256 + tid;
            int r = q >> 3;
            int cs = (q & 7) ^ (r & 7);
            gl2lds16(Aq + (size_t)(m0 + r) * ND + kt + cs * 8,
                     As + (size_t)(j * 256 + wave * 64) * 8);
            int nr = n0 + r; nr = nr < NB ? nr : NB - 1;
            gl2lds16(Bq + (size_t)nr * ND + kt + cs * 8,
                     Bs + (size_t)(j * 256 + wave * 64) * 8);
        }
        __syncthreads();
        #pragma unroll
        for (int kq = 0; kq < 2; ++kq) {
            bf16x8 af[4], bfr[4];
            #pragma unroll
            for (int mi = 0; mi < 4; ++mi) {
                int r = wm * 64 + mi * 16 + lr;
                int ch = (kq * 4 + quad) ^ (lr & 7);
                af[mi] = *(const bf16x8*)(As + (r * 8 + ch) * 8);
            }
            #pragma unroll
            for (int ni = 0; ni < 4; ++ni) {
                int r = wn * 64 + ni * 16 + lr;
                int ch = (kq * 4 + quad) ^ (lr & 7);
                bfr[ni] = *(const bf16x8*)(Bs + (r * 8 + ch) * 8);
            }
            #pragma unroll
            for (int mi = 0; mi < 4; ++mi)
                #pragma unroll
                for (int ni = 0; ni < 4; ++ni)
                    acc[mi][ni] = __builtin_amdgcn_mfma_f32_16x16x32_bf16(
                        af[mi], bfr[ni], acc[mi][ni], 0, 0, 0);
        }
    }

    // C/D layout (verified m89/m91): col = lane&15, row = (lane>>4)*4 + reg
    #pragma unroll
    for (int mi = 0; mi < 4; ++mi) {
        #pragma unroll
        for (int ni = 0; ni < 4; ++ni) {
            int col = n0 + wn * 64 + ni * 16 + lr;
            if (col < NB) {
                #pragma unroll
                for (int r = 0; r < 4; ++r) {
                    int row = m0 + wm * 64 + mi * 16 + quad * 4 + r;
                    C[(size_t)row * NB + col] = acc[mi][ni][r];
                }
            }
        }
    }
}

extern "C" void kernel_launch(void* const* d_in, const int* in_sizes, int n_in,
                              void* d_out, int out_size, void* d_ws, size_t ws_size,
                              hipStream_t stream) {
    const float* qry = (const float*)d_in[0];   // (2048, 512)
    const float* ent = (const float*)d_in[1];   // (40000, 512)
    const float* cb  = (const float*)d_in[2];   // (2048, 512)
    float* out = (float*)d_out;                 // [score | vq_loss | idx]

    char* ws = (char*)d_ws;
    const bool pre = ws_size >= 100ull * 1024 * 1024;

    // region0: partial (20.48 MB) during dist/merge, then quantb (40.96 MB).
    // rescore (writer of quantb) runs after cand_merge (last reader of partial).
    float4*         partial = (float4*)(ws);
    unsigned short* quantb  = (unsigned short*)(ws);
    size_t off = 40960000;
    unsigned short* ehi = nullptr;
    if (pre) { ehi = (unsigned short*)(ws + off); off += 40960000; }
    unsigned short* chi = (unsigned short*)(ws + off); off += 2097152;
    unsigned short* qb  = (unsigned short*)(ws + off); off += 2097152;
    int*            cand= (int*)(ws + off);            off += 1280000;
    float*          c2  = (float*)(ws + off);          off += 8192;
    float*          acc = (float*)(ws + off);          off += 4;

    hipMemsetAsync(acc, 0, sizeof(float), stream);

    c2_kernel<<<NK / 4, 256, 0, stream>>>(cb, c2);
    cvt_bf16_kernel<<<NK * ND / 1024, 256, 0, stream>>>(cb, chi);
    cvt_bf16_kernel<<<Q * ND / 1024, 256, 0, stream>>>(qry, qb);
    if (pre) {
        cvt_bf16_kernel<<<NB * ND / 1024, 256, 0, stream>>>(ent, ehi);
        dist_mfma_kernel<true><<<dim3(313, 16), 256, 0, stream>>>(
            ent, ehi, chi, c2, partial);
    } else {
        dist_mfma_kernel<false><<<dim3(313, 16), 256, 0, stream>>>(
            ent, nullptr, chi, c2, partial);
    }
    cand_merge_kernel<<<(NB + 255) / 256, 256, 0, stream>>>(partial, cand);
    rescore_kernel<<<NB, 512, 0, stream>>>(ent, cb, c2, cand, quantb,
                                           out + SCORE_SIZE + 1, acc);
    vq_final_kernel<<<1, 1, 0, stream>>>(acc, out + SCORE_SIZE);
    score_kernel<<<dim3(313, 16), 256, 0, stream>>>(qb, quantb, out);
}